// Round 20
// baseline (259.614 us; speedup 1.0000x reference)
//
#include <hip/hip_runtime.h>
#include <hip/hip_bf16.h>
#include <hip/hip_cooperative_groups.h>

// SelfAttention: B=4, S=4096, Din=768, Dout=64.
// R20: fuse convert_w + qkv_proj + attn into ONE cooperative kernel with two
//  grid.sync()s. R19's kernels sum to ~45us but dur=51.6 -> ~6.5us of
//  inter-kernel graph gaps, now the largest addressable item. Phase bodies
//  byte-identical to R19; shared memory union-carved (139264B -> 1 block/CU
//  = 256 co-resident blocks, the cooperative requirement). Cross-phase:
//  phase-1 wrap-prefetch drained by its own vmcnt(0)+barrier; grid.sync
//  (+threadfence) makes q/k/vT visible across XCD L2s. Runtime fallback to
//  the 3-kernel R19 path if cooperative launch errors under graph capture.

namespace cg = cooperative_groups;

typedef __attribute__((ext_vector_type(8))) __bf16 bf16x8;
typedef __attribute__((ext_vector_type(4))) __bf16 bf16x4;
typedef __attribute__((ext_vector_type(4))) float  f32x4;

constexpr int BATCH = 4;
constexpr int SEQ   = 4096;
constexpr int DIN   = 768;
constexpr int NTOT  = 192;
constexpr int MROWS = BATCH * SEQ;  // 16384
constexpr int KVT   = 128;

__device__ __forceinline__ f32x4 mfma16(bf16x8 a, bf16x8 b, f32x4 c) {
    return __builtin_amdgcn_mfma_f32_16x16x32_bf16(a, b, c, 0, 0, 0);
}

__device__ __forceinline__ void gload_lds16(const void* g, void* l) {
    __builtin_amdgcn_global_load_lds(
        (const __attribute__((address_space(1))) void*)g,
        (__attribute__((address_space(3))) void*)l, 16, 0, 0);
}

// ==================== phase bodies (shared by fused + fallback) ==========

__device__ __forceinline__ void convert_body(
        int bid, int tid, const float* Wq, const float* Wk, const float* Wv,
        __bf16* wb, int nthreads_total) {
    for (int i = bid * blockDim.x + tid; i < NTOT * DIN; i += nthreads_total) {
        int n = i / DIN;
        const float* src = (n < 64) ? Wq : (n < 128) ? Wk : Wv;
        float scale = (n < 64) ? 0.125f * 1.44269504f : 1.0f;
        wb[i] = (__bf16)(src[(n & 63) * DIN + (i % DIN)] * scale);
    }
}

// proj: 64-row block, 16 waves = 4 strips x 4 n-quarters. smem >= 139264 B.
__device__ __forceinline__ void proj_body(
        int bid, int tid, char* smem,
        const float* x, const __bf16* wb,
        __bf16* q, __bf16* k, __bf16* vT) {
    const int wave = tid >> 6, lane = tid & 63;
    const int strip = wave & 3, nh = wave >> 2;
    const int lr = lane & 15;
    const int g  = lane >> 4;
    const int rx = (lr & 7) << 4;

    char (*wbuf)[NTOT * 128] = (char(*)[NTOT * 128])(smem);            // 73728
    char (*xbuf)[64 * 256]   = (char(*)[64 * 256])(smem + 73728);     // 65536

    const int  srow = lane >> 3;
    const int  ssw  = ((lane & 7) << 4) ^ ((srow & 7) << 4);
    const int  xs4  = lane >> 4;
    const char* wbb = (const char*)wb;
    const char* xbb = (const char*)x;
    const int  xrow0 = bid * 64;

    const int wi0 = wave;
    const int wi1 = (wave + 16) % 24;
    const int xrow = wave * 4 + xs4;
    const int sswx = ((lane & 15) ^ (xrow & 15)) << 4;

    auto stage_w = [&](int buf, int kt) {
#pragma unroll
        for (int s = 0; s < 2; ++s) {
            const int wi = (s == 0) ? wi0 : wi1;
            gload_lds16(wbb + (size_t)(wi * 8 + srow) * (DIN * 2) + kt * 128 + ssw,
                        &wbuf[buf][wi * 8 * 128]);
        }
    };
    auto stage_x = [&](int buf, int kt) {
        gload_lds16(xbb + (size_t)(xrow0 + xrow) * (DIN * 4) + kt * 256 + sswx,
                    &xbuf[buf][wave * 4 * 256]);
    };

    f32x4 acc[3];
#pragma unroll
    for (int t = 0; t < 3; ++t) acc[t] = f32x4{0.f, 0.f, 0.f, 0.f};

    stage_w(0, 0);
    stage_x(0, 0);
    stage_x(1, 1);
    asm volatile("s_waitcnt vmcnt(1) lgkmcnt(0)" ::: "memory");
    __builtin_amdgcn_s_barrier();

    constexpr int NT = DIN / 64;   // 12
    for (int kt = 0; kt < NT; ++kt) {
        stage_w((kt + 1) % 3, (kt + 1) % NT);
        stage_x((kt + 2) & 3, (kt + 2) % NT);
        asm volatile("s_waitcnt vmcnt(4) lgkmcnt(0)" ::: "memory");
        __builtin_amdgcn_s_barrier();

        const char* wbc = wbuf[kt % 3];
        const char* xbc = xbuf[kt & 3];
#pragma unroll
        for (int ks = 0; ks < 2; ++ks) {
            const char* xrp = xbc + (strip * 16 + lr) * 256;
            f32x4 xa = *(const f32x4*)(xrp + ((ks * 128 + g * 32)      ^ (lr << 4)));
            f32x4 xb = *(const f32x4*)(xrp + ((ks * 128 + g * 32 + 16) ^ (lr << 4)));
            bf16x8 af;
            af[0] = (__bf16)xa[0]; af[1] = (__bf16)xa[1]; af[2] = (__bf16)xa[2]; af[3] = (__bf16)xa[3];
            af[4] = (__bf16)xb[0]; af[5] = (__bf16)xb[1]; af[6] = (__bf16)xb[2]; af[7] = (__bf16)xb[3];
#pragma unroll
            for (int t = 0; t < 3; ++t) {
                const int nr = (nh * 3 + t) * 16 + lr;
                bf16x8 bf = *(const bf16x8*)(wbc + nr * 128 +
                                             ((ks * 64 + g * 16) ^ rx));
                acc[t] = mfma16(af, bf, acc[t]);
            }
        }
    }

    // q/k direct stores
    const int orow_l = strip * 16 + g * 4;
#pragma unroll
    for (int t = 0; t < 3; ++t) {
        const int n = (nh * 3 + t) * 16 + lr;
        if (n < 128) {
#pragma unroll
            for (int r = 0; r < 4; ++r) {
                const int m = bid * 64 + orow_l + r;
                __bf16 hv = (__bf16)acc[t][r];
                if (n < 64) q[(size_t)m * 64 + n] = hv;
                else        k[(size_t)m * 64 + (n - 64)] = hv;
            }
        }
    }

    // vT via LDS transpose (dead xbuf[0]; drain wrap-prefetch first)
    asm volatile("s_waitcnt vmcnt(0) lgkmcnt(0)" ::: "memory");
    __syncthreads();
    char* vt = &xbuf[0][0];
#pragma unroll
    for (int t = 0; t < 3; ++t) {
        const int n = (nh * 3 + t) * 16 + lr;
        if (n >= 128) {
            const int nn  = n - 128;
            const int key = (nn & 7) << 4;
#pragma unroll
            for (int r = 0; r < 4; ++r) {
                const int mm = orow_l + r;
                *(__bf16*)(vt + nn * 128 + ((mm * 2) ^ key)) = (__bf16)acc[t][r];
            }
        }
    }
    __syncthreads();
    if (wave < 8) {
        const int nn = wave * 8 + (lane >> 3);
        const int s  = lane & 7;
        const int sl = s ^ (nn & 7);
        bf16x8 vv = *(const bf16x8*)(vt + nn * 128 + s * 16);
        __bf16* dst = vT + (size_t)(bid >> 6) * 64 * SEQ
                    + (size_t)nn * SEQ + (bid & 63) * 64 + sl * 8;
        *(bf16x8*)dst = vv;
    }
}

// attn: 16 waves (4 q-strips x 4 kv-parities), KVT=128. smem >= 131072 B.
__device__ __forceinline__ void attn_body(
        int b, int bx, int tid, char* smem,
        const __bf16* q, const __bf16* k, const __bf16* vT, float* out) {
    const int wave = tid >> 6, lane = tid & 63;
    const int strip = wave & 3, par = wave >> 2;
    const int q0 = bx * 64 + strip * 16;
    const int lr = lane & 15;
    const int g  = lane >> 4;
    const int lk = g * 8;
    const int rx = (lr & 7) << 4;

    const __bf16* qp = q  + (size_t)b * SEQ * 64;
    const __bf16* kp = k  + (size_t)b * SEQ * 64;
    const __bf16* vp = vT + (size_t)b * 64 * SEQ;

    char (*kbuf)[KVT * 128] = (char(*)[KVT * 128])(smem);          // 49152
    char (*vbuf)[64 * 256]  = (char(*)[64 * 256])(smem + 49152);   // 49152
    char (*pbuf)[2048]      = (char(*)[2048])(smem + 98304);       // 32768
    char* pw = pbuf[wave];

    const int  srow8 = lane >> 3;
    const int  sswK  = ((lane & 7) << 4) ^ ((srow8 & 7) << 4);
    const int  vrow  = wave * 4 + (lane >> 4);
    const int  sswV  = ((lane & 15) ^ (vrow & 7)) << 4;

    auto stage = [&](int buf, int kv0) {
        gload_lds16((const char*)kp + (size_t)(kv0 + wave * 8 + srow8) * 128 + sswK,
                    &kbuf[buf][wave * 8 * 128]);
        gload_lds16((const char*)vp + (size_t)vrow * (SEQ * 2) +
                        (size_t)kv0 * 2 + sswV,
                    &vbuf[buf][wave * 4 * 256]);
    };

    bf16x8 qf0 = *(const bf16x8*)(qp + (size_t)(q0 + lr) * 64 + lk);
    bf16x8 qf1 = *(const bf16x8*)(qp + (size_t)(q0 + lr) * 64 + 32 + lk);

    f32x4 acc_o[4];
#pragma unroll
    for (int t = 0; t < 4; ++t) acc_o[t] = f32x4{0.f, 0.f, 0.f, 0.f};
    float l_run = 0.f;

    stage(0, 0);
    asm volatile("s_waitcnt vmcnt(0) lgkmcnt(0)" ::: "memory");
    __builtin_amdgcn_s_barrier();

    constexpr int NT = SEQ / KVT;   // 32
    int cur = 0, nxt = 1;
    for (int it = 0; it < NT; ++it) {
        stage(nxt, ((it + 1) & (NT - 1)) * KVT);
        asm volatile("s_waitcnt vmcnt(2) lgkmcnt(0)" ::: "memory");
        __builtin_amdgcn_s_barrier();

        f32x4 s4[2];
#pragma unroll
        for (int j = 0; j < 2; ++j) {
            const char* kr = &kbuf[cur][(par * 32 + j * 16 + lr) * 128];
            bf16x8 kf0 = *(const bf16x8*)(kr + ((g * 16) ^ rx));
            bf16x8 kf1 = *(const bf16x8*)(kr + ((64 + g * 16) ^ rx));
            f32x4 a = f32x4{0.f, 0.f, 0.f, 0.f};
            a = mfma16(kf0, qf0, a);
            a = mfma16(kf1, qf1, a);
            s4[j] = a;
        }

#pragma unroll
        for (int j = 0; j < 2; ++j) {
            bf16x4 pbv;
#pragma unroll
            for (int r = 0; r < 4; ++r) {
                float p = __builtin_amdgcn_exp2f(s4[j][r]);
                l_run += p;
                pbv[r] = (__bf16)p;
            }
            *(bf16x4*)(pw + lr * 128 + ((j * 32 + g * 8) ^ rx)) = pbv;
        }
        asm volatile("s_waitcnt lgkmcnt(0)" ::: "memory");

        bf16x8 pf = *(const bf16x8*)(pw + lr * 128 + ((g * 16) ^ rx));
#pragma unroll
        for (int t = 0; t < 4; ++t) {
            const char* vr = &vbuf[cur][(t * 16 + lr) * 256];
            bf16x8 vf = *(const bf16x8*)(vr + ((par * 64 + g * 16) ^ rx));
            acc_o[t] = mfma16(vf, pf, acc_o[t]);
        }

        cur = nxt; nxt = (nxt == 2) ? 0 : nxt + 1;
    }

    l_run += __shfl_xor(l_run, 16);
    l_run += __shfl_xor(l_run, 32);
    __syncthreads();

    float* mo = (float*)&kbuf[0][0];
    float* ml = (float*)&vbuf[0][0];
    if (par > 0) {
        const int pi = par - 1;
        float* dst = mo + (size_t)((pi * 4 + strip) * 16 + lr) * 64;
#pragma unroll
        for (int t = 0; t < 4; ++t)
            *(f32x4*)(dst + t * 16 + g * 4) = acc_o[t];
        if (lane < 16) ml[(pi * 4 + strip) * 16 + lr] = l_run;
    }
    __syncthreads();
    if (par == 0) {
        float L = l_run;
#pragma unroll
        for (int pi = 0; pi < 3; ++pi) L += ml[(pi * 4 + strip) * 16 + lr];
        float inv = 1.f / L;
        float* ob = out + ((size_t)b * SEQ + q0 + lr) * 64;
#pragma unroll
        for (int t = 0; t < 4; ++t) {
            f32x4 o4 = acc_o[t];
#pragma unroll
            for (int pi = 0; pi < 3; ++pi)
                o4 += *(const f32x4*)(mo + (size_t)((pi * 4 + strip) * 16 + lr) * 64 +
                                      t * 16 + g * 4);
#pragma unroll
            for (int r = 0; r < 4; ++r) o4[r] *= inv;
            *(f32x4*)(ob + t * 16 + g * 4) = o4;
        }
    }
}

// ==================== fused cooperative kernel ===========================

__global__ __launch_bounds__(1024, 4) void fused(
        const float* __restrict__ x, const float* __restrict__ Wq,
        const float* __restrict__ Wk, const float* __restrict__ Wv,
        __bf16* wb, __bf16* q, __bf16* k, __bf16* vT, float* out) {
    __shared__ __align__(16) char smem[139264];
    cg::grid_group grid = cg::this_grid();
    const int bid = blockIdx.x;
    const int tid = threadIdx.x;

    // phase 0: convert W
    convert_body(bid, tid, Wq, Wk, Wv, wb, 256 * 1024);
    __threadfence();
    grid.sync();

    // phase 1: qkv projection
    proj_body(bid, tid, smem, x, wb, q, k, vT);
    __threadfence();
    grid.sync();

    // phase 2: attention (b = bid>>6, bx = bid&63)
    attn_body(bid >> 6, bid & 63, tid, smem, q, k, vT, out);
}

// ==================== fallback standalone kernels (R19) ==================

__global__ __launch_bounds__(256) void convert_w(
        const float* __restrict__ Wq, const float* __restrict__ Wk,
        const float* __restrict__ Wv, __bf16* __restrict__ wb) {
    int i = blockIdx.x * 256 + threadIdx.x;
    if (i >= NTOT * DIN) return;
    int n = i / DIN;
    const float* src = (n < 64) ? Wq : (n < 128) ? Wk : Wv;
    float scale = (n < 64) ? 0.125f * 1.44269504f : 1.0f;
    wb[i] = (__bf16)(src[(n & 63) * DIN + (i % DIN)] * scale);
}

__global__ __launch_bounds__(1024, 4) void qkv_proj(
        const float* __restrict__ x, const __bf16* __restrict__ wb,
        __bf16* __restrict__ q, __bf16* __restrict__ k, __bf16* __restrict__ vT) {
    __shared__ __align__(16) char smem[139264];
    proj_body(blockIdx.x, threadIdx.x, smem, x, wb, q, k, vT);
}

__global__ __launch_bounds__(1024, 4) void attn(
        const __bf16* __restrict__ q, const __bf16* __restrict__ k,
        const __bf16* __restrict__ vT, float* __restrict__ out) {
    __shared__ __align__(16) char smem[131072];
    attn_body(blockIdx.y, blockIdx.x, threadIdx.x, smem, q, k, vT, out);
}

extern "C" void kernel_launch(void* const* d_in, const int* in_sizes, int n_in,
                              void* d_out, int out_size, void* d_ws, size_t ws_size,
                              hipStream_t stream) {
    const float* x  = (const float*)d_in[0];
    const float* Wq = (const float*)d_in[1];
    const float* Wk = (const float*)d_in[2];
    const float* Wv = (const float*)d_in[3];
    float* out = (float*)d_out;

    char* ws = (char*)d_ws;
    __bf16* wb = (__bf16*)(ws);
    __bf16* qb = (__bf16*)(ws + 294912);
    __bf16* kb = (__bf16*)(ws + 294912 + 2097152);
    __bf16* vT = (__bf16*)(ws + 294912 + 2u * 2097152);

    void* args[] = {(void*)&x, (void*)&Wq, (void*)&Wk, (void*)&Wv,
                    (void*)&wb, (void*)&qb, (void*)&kb, (void*)&vT, (void*)&out};
    hipError_t e = hipLaunchCooperativeKernel((const void*)fused, dim3(256),
                                              dim3(1024), args, 0, stream);
    if (e != hipSuccess) {
        // fallback: validated R19 3-kernel path
        convert_w<<<dim3((NTOT * DIN + 255) / 256), dim3(256), 0, stream>>>(
            Wq, Wk, Wv, wb);
        qkv_proj<<<dim3(MROWS / 64), dim3(1024), 0, stream>>>(x, wb, qb, kb, vT);
        attn<<<dim3(SEQ / 64, BATCH), dim3(1024), 0, stream>>>(qb, kb, vT, out);
    }
}

// Round 21
// 51.654 us; speedup vs baseline: 5.0261x; 5.0261x over previous
//
#include <hip/hip_runtime.h>
#include <hip/hip_bf16.h>

// SelfAttention: B=4, S=4096, Din=768, Dout=64.
// R21 = byte-exact revert to R19 (best validated: 51.58us).
//  R20's cooperative fusion ran at ~293us: grid.sync (cross-XCD atomic spin
//  + threadfence cache flush semantics) costs orders of magnitude more than
//  the ~6.5us of graph-replay kernel gaps it targeted. Mechanism understood;
//  fusion abandoned.
//  State: proj = 16-wave, wb 3-buf 1-ahead + x 4-buf 2-ahead (vmcnt(4)),
//  vT via LDS-transpose epilogue. attn = 16-wave (4 q-strips x 4 kv-par),
//  KVT=128 triple-buffer counted vmcnt(2), max-free exp2 softmax, LDS P
//  round-trip. Both main loops at their LDS-instruction-issue ceilings
//  (R15-R18: three falsified restructures, two confirmed micro-wins).

typedef __attribute__((ext_vector_type(8))) __bf16 bf16x8;
typedef __attribute__((ext_vector_type(4))) __bf16 bf16x4;
typedef __attribute__((ext_vector_type(4))) float  f32x4;

constexpr int BATCH = 4;
constexpr int SEQ   = 4096;
constexpr int DIN   = 768;
constexpr int NTOT  = 192;
constexpr int MROWS = BATCH * SEQ;  // 16384
constexpr int KVT   = 128;          // kv tile (128 rows x 128B K, 64 x 256B V)

__device__ __forceinline__ f32x4 mfma16(bf16x8 a, bf16x8 b, f32x4 c) {
    return __builtin_amdgcn_mfma_f32_16x16x32_bf16(a, b, c, 0, 0, 0);
}

__device__ __forceinline__ void gload_lds16(const void* g, void* l) {
    __builtin_amdgcn_global_load_lds(
        (const __attribute__((address_space(1))) void*)g,
        (__attribute__((address_space(3))) void*)l, 16, 0, 0);
}

// ---------------- k0: pack Wq|Wk|Wv -> bf16 [192][768]; Wq pre-scaled by
// 0.125*log2(e) so attention scores come out in exp2 domain.
__global__ __launch_bounds__(256) void convert_w(
        const float* __restrict__ Wq, const float* __restrict__ Wk,
        const float* __restrict__ Wv, __bf16* __restrict__ wb) {
    int i = blockIdx.x * 256 + threadIdx.x;
    if (i >= NTOT * DIN) return;
    int n = i / DIN;
    const float* src = (n < 64) ? Wq : (n < 128) ? Wk : Wv;
    float scale = (n < 64) ? 0.125f * 1.44269504f : 1.0f;
    wb[i] = (__bf16)(src[(n & 63) * DIN + (i % DIN)] * scale);
}

// ---------------- k1: q,k,v = x @ W^T  (M=16384, N=192, K=768)
// grid = 256 blocks of 64 rows; 16 waves = 4 row-strips x 4 n-quarters
// (3 n-tiles each). wb: 3 bufs staged 1 ahead; x: 4 bufs staged 2 ahead.
// Per-wave per-iter staging = 2 wb + 1 x ops -> steady vmcnt(4).
__global__ __launch_bounds__(1024, 4) void qkv_proj(
        const float* __restrict__ x, const __bf16* __restrict__ wb,
        __bf16* __restrict__ q, __bf16* __restrict__ k, __bf16* __restrict__ vT) {
    const int tid  = threadIdx.x;
    const int wave = tid >> 6, lane = tid & 63;
    const int strip = wave & 3, nh = wave >> 2;   // 4 strips x 4 n-quarters
    const int lr = lane & 15;
    const int g  = lane >> 4;
    const int rx = (lr & 7) << 4;

    __shared__ __align__(16) char wbuf[3][NTOT * 128];   // 72 KiB
    __shared__ __align__(16) char xbuf[4][64 * 256];     // 64 KiB

    const int  srow = lane >> 3;                          // wb: 8 rows/instr
    const int  ssw  = ((lane & 7) << 4) ^ ((srow & 7) << 4);
    const int  xs4  = lane >> 4;                          // x: 4 rows/instr
    const char* wbb = (const char*)wb;
    const char* xbb = (const char*)x;
    const int  xrow0 = blockIdx.x * 64;

    // wb instr assignment: wave w covers instrs w and (w+16)%24 (waves
    // 8..15's second instr duplicates rows 0..63 — identical bytes, benign).
    const int wi0 = wave;
    const int wi1 = (wave + 16) % 24;
    // x instr assignment: wave w covers rows [w*4, w*4+4) (4 rows of 256B).
    const int xrow = wave * 4 + xs4;
    const int sswx = ((lane & 15) ^ (xrow & 15)) << 4;

    auto stage_w = [&](int buf, int kt) {
#pragma unroll
        for (int s = 0; s < 2; ++s) {
            const int wi = (s == 0) ? wi0 : wi1;
            gload_lds16(wbb + (size_t)(wi * 8 + srow) * (DIN * 2) + kt * 128 + ssw,
                        &wbuf[buf][wi * 8 * 128]);
        }
    };
    auto stage_x = [&](int buf, int kt) {
        gload_lds16(xbb + (size_t)(xrow0 + xrow) * (DIN * 4) + kt * 256 + sswx,
                    &xbuf[buf][wave * 4 * 256]);
    };

    f32x4 acc[3];
#pragma unroll
    for (int t = 0; t < 3; ++t) acc[t] = f32x4{0.f, 0.f, 0.f, 0.f};

    stage_w(0, 0);
    stage_x(0, 0);
    stage_x(1, 1);
    asm volatile("s_waitcnt vmcnt(1) lgkmcnt(0)" ::: "memory");  // W0,X0 done
    __builtin_amdgcn_s_barrier();

    constexpr int NT = DIN / 64;   // 12
    for (int kt = 0; kt < NT; ++kt) {
        stage_w((kt + 1) % 3, (kt + 1) % NT);             // wrap: count const
        stage_x((kt + 2) & 3, (kt + 2) % NT);
        asm volatile("s_waitcnt vmcnt(4) lgkmcnt(0)" ::: "memory");
        __builtin_amdgcn_s_barrier();

        const char* wbc = wbuf[kt % 3];
        const char* xbc = xbuf[kt & 3];
#pragma unroll
        for (int ks = 0; ks < 2; ++ks) {
            const char* xrp = xbc + (strip * 16 + lr) * 256;
            f32x4 xa = *(const f32x4*)(xrp + ((ks * 128 + g * 32)      ^ (lr << 4)));
            f32x4 xb = *(const f32x4*)(xrp + ((ks * 128 + g * 32 + 16) ^ (lr << 4)));
            bf16x8 af;
            af[0] = (__bf16)xa[0]; af[1] = (__bf16)xa[1]; af[2] = (__bf16)xa[2]; af[3] = (__bf16)xa[3];
            af[4] = (__bf16)xb[0]; af[5] = (__bf16)xb[1]; af[6] = (__bf16)xb[2]; af[7] = (__bf16)xb[3];
#pragma unroll
            for (int t = 0; t < 3; ++t) {
                const int nr = (nh * 3 + t) * 16 + lr;
                bf16x8 bf = *(const bf16x8*)(wbc + nr * 128 +
                                             ((ks * 64 + g * 16) ^ rx));
                acc[t] = mfma16(af, bf, acc[t]);
            }
        }
    }

    // ---- epilogue: q/k direct (coalesced-enough, wave-uniform branches)
    const int orow_l = strip * 16 + g * 4;   // m within block, 0..63 (+r)
#pragma unroll
    for (int t = 0; t < 3; ++t) {
        const int n = (nh * 3 + t) * 16 + lr;
        if (n < 128) {
#pragma unroll
            for (int r = 0; r < 4; ++r) {
                const int m = blockIdx.x * 64 + orow_l + r;
                __bf16 hv = (__bf16)acc[t][r];
                if (n < 64) q[(size_t)m * 64 + n] = hv;
                else        k[(size_t)m * 64 + (n - 64)] = hv;
            }
        }
    }

    // ---- vT via LDS transpose. Drain wrap-prefetch (it writes xbuf[0/1]!)
    // then reuse xbuf[0] as vt[64 d][128B m], XOR key (nn&7)<<4 (2-way, free).
    asm volatile("s_waitcnt vmcnt(0) lgkmcnt(0)" ::: "memory");
    __syncthreads();
    char* vt = &xbuf[0][0];   // 8 KiB used
#pragma unroll
    for (int t = 0; t < 3; ++t) {
        const int n = (nh * 3 + t) * 16 + lr;
        if (n >= 128) {
            const int nn  = n - 128;
            const int key = (nn & 7) << 4;
#pragma unroll
            for (int r = 0; r < 4; ++r) {
                const int mm = orow_l + r;
                *(__bf16*)(vt + nn * 128 + ((mm * 2) ^ key)) = (__bf16)acc[t][r];
            }
        }
    }
    __syncthreads();
    // coalesced store: waves 0..7 cover 8 d-rows each (8 lanes x 16B / row).
    // physical slot s of row nn holds logical m-block sl = s ^ (nn&7).
    if (wave < 8) {
        const int nn = wave * 8 + (lane >> 3);
        const int s  = lane & 7;
        const int sl = s ^ (nn & 7);
        bf16x8 vv = *(const bf16x8*)(vt + nn * 128 + s * 16);
        __bf16* dst = vT + (size_t)(blockIdx.x >> 6) * 64 * SEQ
                    + (size_t)nn * SEQ + (blockIdx.x & 63) * 64 + sl * 8;
        *(bf16x8*)dst = vv;
    }
}

// ---------------- k2: flash attention, LDS-staged K/V, 16 waves.  [= R14]
// grid = (SEQ/64, BATCH) = 256 blocks, 1024 threads
// (4 q-strips x 4 kv-parities). Triple-buffered, counted vmcnt(2).
__global__ __launch_bounds__(1024, 4) void attn(
        const __bf16* __restrict__ q, const __bf16* __restrict__ k,
        const __bf16* __restrict__ vT, float* __restrict__ out) {
    const int tid  = threadIdx.x;
    const int wave = tid >> 6, lane = tid & 63;
    const int strip = wave & 3, par = wave >> 2;
    const int b  = blockIdx.y;
    const int q0 = blockIdx.x * 64 + strip * 16;
    const int lr = lane & 15;
    const int g  = lane >> 4;
    const int lk = g * 8;
    const int rx = (lr & 7) << 4;

    const __bf16* qp = q  + (size_t)b * SEQ * 64;
    const __bf16* kp = k  + (size_t)b * SEQ * 64;
    const __bf16* vp = vT + (size_t)b * 64 * SEQ;

    __shared__ __align__(16) char kbuf[3][KVT * 128];   // 48 KiB (128r x 128B)
    __shared__ __align__(16) char vbuf[3][64 * 256];    // 48 KiB (64r x 256B)
    __shared__ __align__(16) char pbuf[16][2048];       // 32 KiB
    char* pw = &pbuf[wave][0];

    const int  srow8 = lane >> 3;                        // K: 8 rows/instr
    const int  sswK  = ((lane & 7) << 4) ^ ((srow8 & 7) << 4);
    const int  vrow  = wave * 4 + (lane >> 4);           // V: 4 rows/instr
    const int  sswV  = ((lane & 15) ^ (vrow & 7)) << 4;

    auto stage = [&](int buf, int kv0) {   // exactly 2 VMEM ops per wave
        gload_lds16((const char*)kp + (size_t)(kv0 + wave * 8 + srow8) * 128 + sswK,
                    &kbuf[buf][wave * 8 * 128]);
        gload_lds16((const char*)vp + (size_t)vrow * (SEQ * 2) +
                        (size_t)kv0 * 2 + sswV,
                    &vbuf[buf][wave * 4 * 256]);
    };

    bf16x8 qf0 = *(const bf16x8*)(qp + (size_t)(q0 + lr) * 64 + lk);
    bf16x8 qf1 = *(const bf16x8*)(qp + (size_t)(q0 + lr) * 64 + 32 + lk);

    f32x4 acc_o[4];
#pragma unroll
    for (int t = 0; t < 4; ++t) acc_o[t] = f32x4{0.f, 0.f, 0.f, 0.f};
    float l_run = 0.f;

    stage(0, 0);
    asm volatile("s_waitcnt vmcnt(0) lgkmcnt(0)" ::: "memory");
    __builtin_amdgcn_s_barrier();

    constexpr int NT = SEQ / KVT;   // 32
    int cur = 0, nxt = 1;
    for (int it = 0; it < NT; ++it) {
        stage(nxt, ((it + 1) & (NT - 1)) * KVT);          // wrap keeps count const
        asm volatile("s_waitcnt vmcnt(2) lgkmcnt(0)" ::: "memory");
        __builtin_amdgcn_s_barrier();

        // ---- S^T = K Q^T on parity's 32 kv rows (exp2 domain)
        f32x4 s4[2];
#pragma unroll
        for (int j = 0; j < 2; ++j) {
            const char* kr = &kbuf[cur][(par * 32 + j * 16 + lr) * 128];
            bf16x8 kf0 = *(const bf16x8*)(kr + ((g * 16) ^ rx));
            bf16x8 kf1 = *(const bf16x8*)(kr + ((64 + g * 16) ^ rx));
            f32x4 a = f32x4{0.f, 0.f, 0.f, 0.f};
            a = mfma16(kf0, qf0, a);
            a = mfma16(kf1, qf1, a);
            s4[j] = a;
        }

        // ---- max-free softmax; pack P (16q x 32kv, swizzled rows of 128B)
#pragma unroll
        for (int j = 0; j < 2; ++j) {
            bf16x4 pbv;
#pragma unroll
            for (int r = 0; r < 4; ++r) {
                float p = __builtin_amdgcn_exp2f(s4[j][r]);
                l_run += p;
                pbv[r] = (__bf16)p;
            }
            *(bf16x4*)(pw + lr * 128 + ((j * 32 + g * 8) ^ rx)) = pbv;
        }
        asm volatile("s_waitcnt lgkmcnt(0)" ::: "memory");

        // ---- O^T += V^T P on parity's kv slice (one 32-wide K-step)
        bf16x8 pf = *(const bf16x8*)(pw + lr * 128 + ((g * 16) ^ rx));
#pragma unroll
        for (int t = 0; t < 4; ++t) {
            const char* vr = &vbuf[cur][(t * 16 + lr) * 256];
            bf16x8 vf = *(const bf16x8*)(vr + ((par * 64 + g * 16) ^ rx));
            acc_o[t] = mfma16(vf, pf, acc_o[t]);
        }

        cur = nxt; nxt = (nxt == 2) ? 0 : nxt + 1;
    }

    // ---- 4-parity merge (plain sums: max-free). kbuf/vbuf dead -> reuse.
    l_run += __shfl_xor(l_run, 16);
    l_run += __shfl_xor(l_run, 32);
    __syncthreads();   // full drain (incl. wrap prefetch) before LDS reuse

    float* mo = (float*)(&kbuf[0][0]);   // [3][4][16][64] f32 = 48 KiB
    float* ml = (float*)(&vbuf[0][0]);   // [3][4][16] f32
    if (par > 0) {
        const int pi = par - 1;
        float* dst = mo + (size_t)((pi * 4 + strip) * 16 + lr) * 64;
#pragma unroll
        for (int t = 0; t < 4; ++t)
            *(f32x4*)(dst + t * 16 + g * 4) = acc_o[t];
        if (lane < 16) ml[(pi * 4 + strip) * 16 + lr] = l_run;
    }
    __syncthreads();
    if (par == 0) {
        float L = l_run;
#pragma unroll
        for (int pi = 0; pi < 3; ++pi) L += ml[(pi * 4 + strip) * 16 + lr];
        float inv = 1.f / L;
        float* ob = out + ((size_t)b * SEQ + q0 + lr) * 64;
#pragma unroll
        for (int t = 0; t < 4; ++t) {
            f32x4 o4 = acc_o[t];
#pragma unroll
            for (int pi = 0; pi < 3; ++pi)
                o4 += *(const f32x4*)(mo + (size_t)((pi * 4 + strip) * 16 + lr) * 64 +
                                      t * 16 + g * 4);
#pragma unroll
            for (int r = 0; r < 4; ++r) o4[r] *= inv;
            *(f32x4*)(ob + t * 16 + g * 4) = o4;
        }
    }
}

extern "C" void kernel_launch(void* const* d_in, const int* in_sizes, int n_in,
                              void* d_out, int out_size, void* d_ws, size_t ws_size,
                              hipStream_t stream) {
    const float* x  = (const float*)d_in[0];
    const float* Wq = (const float*)d_in[1];
    const float* Wk = (const float*)d_in[2];
    const float* Wv = (const float*)d_in[3];
    float* out = (float*)d_out;

    char* ws = (char*)d_ws;
    __bf16* wb = (__bf16*)(ws);
    __bf16* qb = (__bf16*)(ws + 294912);
    __bf16* kb = (__bf16*)(ws + 294912 + 2097152);
    __bf16* vT = (__bf16*)(ws + 294912 + 2u * 2097152);

    convert_w<<<dim3((NTOT * DIN + 255) / 256), dim3(256), 0, stream>>>(Wq, Wk, Wv, wb);
    qkv_proj<<<dim3(MROWS / 64), dim3(1024), 0, stream>>>(x, wb, qb, kb, vT);
    attn<<<dim3(SEQ / 64, BATCH), dim3(1024), 0, stream>>>(qb, kb, vT, out);
}